// Round 7
// baseline (163.127 us; speedup 1.0000x reference)
//
#include <hip/hip_runtime.h>
#include <math.h>

// ShadowMapping forward: hard + soft shadow maps, fully fused, single kernel.
// R7: odd-harmonic polynomial identity — f = sum_{m=1,3,5,7} (1/m) sin(m*th)
//     = s*(4 - 13.3333 s^2 + 19.2 s^4 - 9.142857 s^6), s = sin(th) — so each
//     tap costs ONE v_sin + 5 FMA (was 2 trans + ~20 VALU recurrence).
//     4 pixels/thread: float4 depth/mask loads, float4 stores, per-light
//     uniforms (sqrt, divides, exp2) amortized 4x; adjacent stencils share L1
//     lines. Hard-path geometry chain bit-identical to R2..R6 (validated:
//     XLA dot emitter = sequential fmuladd over w). 3x3 blur validated R6.

#define RESN 512
#define NL 16
#define NPIX (RESN*RESN)

__global__ __launch_bounds__(256) void fused_kernel(
    const float* __restrict__ depth,
    const float* __restrict__ mask,
    const float* __restrict__ z_map,
    const float* __restrict__ als,
    float* __restrict__ out,
    float TANHF, float OZF, float OWF)
{
  #pragma clang fp contract(off)
  const float OFFS = -0.0642233295781f;
  const float CLB  = 0.4458709375254f;
  const float TWO_OVER_PI = 0.63661977236758134308f;
  // 4096 blocks: low 3 bits + bit 11 = light (XCD affinity: l === id mod 8),
  // bits [3..10] = 256 pixel-blocks of 1024 px.
  const int id = (int)blockIdx.x;
  const int l  = ((id >> 11) << 3) | (id & 7);
  const int pb = (id >> 3) & 255;
  const int p0 = (pb << 10) + ((int)threadIdx.x << 2);   // 4 consecutive px
  const int r  = p0 >> 9;
  const int c0 = p0 & 511;

  // ---- per-light uniforms (amortized over 4 pixels) ---------------------
  float xd = als[l*7+0], yd = als[l*7+1], zd = als[l*7+2], sg = als[l*7+3];
  float cosp = sqrtf(xd*xd + zd*zd);
  float cost = zd / cosp;
  float sint = xd / cosp;
  float e00 = cost,          e02 = -sint;
  float e10 = (-sint)*yd,    e11 = cosp,  e12 = (-cost)*yd;
  float e20 = cosp*sint,     e21 = yd,    e22 = cosp*cost;
  // radius-1 Gaussian, normalized over the full 21-tap sum (e2 = e1^4,
  // e3.. < 2e-12; tap-2 dropped, weight kept in norm — error ~1e-5)
  float sig = ((2.0f*(6.0f*sg + 1.0f)) - 1.0f) / 6.0f;
  float ivs = 1.0f/(sig*sig);
  float e1  = __builtin_amdgcn_exp2f(-0.72134752044448170368f*ivs);
  float e1sq = e1*e1;
  float e2  = e1sq*e1sq;
  float kinv = 1.0f/(1.0f + 2.0f*e1 + 2.0f*e2);
  float w0 = kinv, w1 = e1*kinv;

  const int base = l << 18;
  float4 dz4 = *(const float4*)(depth + p0);
  float4 mk4 = *(const float4*)(mask  + p0);
  float m1r = 2.0f * ((float)r / 512.0f + 0.0009765625f) - 1.0f;

  float hard_o[4], soft_o[4];
  #pragma unroll
  for (int j = 0; j < 4; ++j) {
    float dz = (j==0)?dz4.x:(j==1)?dz4.y:(j==2)?dz4.z:dz4.w;
    float mk = (j==0)?mk4.x:(j==1)?mk4.y:(j==2)?mk4.z:mk4.w;
    float m1c = 2.0f * ((float)(c0+j) / 512.0f + 0.0009765625f) - 1.0f;
    float tT = dz * TANHF;
    float qx = tT * m1c;
    float qy = tT * m1r;
    float qz = 2.7f - dz;
    // XLA dot emitter: sequential fmuladd over w (validated R2)
    float X1 = fmaf(qz, e02, qx * e00);
    float Y1 = fmaf(qz, e12, fmaf(qy, e11, qx * e10));
    float T2 = fmaf(qz, e22, fmaf(qy, e21, qx * e20));
    float Z1 = T2 + (-2.7f);
    float ZZ = (Z1 * OZF) + OWF;
    float uf = (X1 + 1.0f) * 256.0f;
    float vf = (Y1 + 1.0f) * 256.0f;
    int u = (int)uf; u = u < 0 ? 0 : (u > 511 ? 511 : u);
    int v = (int)vf; v = v < 0 ? 0 : (v > 511 ? 511 : v);
    float dd = 0.5f * (1.0f + ZZ);
    dd = fminf(fmaxf(dd, 0.0f), 1.0f);
    float dpo = dd + OFFS;

    // ---- 9 taps, clamped indices, OOB handled by zero weights -----------
    int u0 = u > 0 ? u - 1 : 0;
    int u2 = u < 511 ? u + 1 : 511;
    int v0 = v > 0 ? v - 1 : 0;
    int v2 = v < 511 ? v + 1 : 511;
    const float* zr0 = z_map + base + (v0 << 9);
    const float* zr1 = z_map + base + (v  << 9);
    const float* zr2 = z_map + base + (v2 << 9);
    float zA = zr0[u0], zB = zr0[u], zC = zr0[u2];
    float zD = zr1[u0], zg = zr1[u], zF = zr1[u2];
    float zG = zr2[u0], zH = zr2[u], zI = zr2[u2];

    float wuL = (u > 0)   ? w1 : 0.0f;
    float wuR = (u < 511) ? w1 : 0.0f;
    float wvT = (v > 0)   ? w1 : 0.0f;
    float wvB = (v < 511) ? w1 : 0.0f;

    // f = sum_{m odd<=7} (1/m) sin(m*pi*(z-dpo)) = s*P(s^2), s = sin(pi*dz')
    auto fval = [&](float z) {
      float s = __builtin_amdgcn_sinf(0.5f * (z - dpo));   // revolutions
      float t = s * s;
      return s * fmaf(t, fmaf(t, fmaf(t, -9.142857142857142f, 19.2f),
                              -13.333333333333334f), 4.0f);
    };

    float rowT = fmaf(wuL, fval(zA), fmaf(w0, fval(zB), wuR * fval(zC)));
    float rowC = fmaf(wuL, fval(zD), fmaf(w0, fval(zg), wuR * fval(zF)));
    float rowB = fmaf(wuL, fval(zG), fmaf(w0, fval(zH), wuR * fval(zI)));
    float q = TWO_OVER_PI * fmaf(wvT, rowT, fmaf(w0, rowC, wvB * rowB));

    float diff = fmaxf(dd - zg, 0.0f);
    hard_o[j] = mk * ((diff > 0.008f) ? 0.0f : 1.0f);
    float qc = fminf(fmaxf(q, -CLB), CLB) / CLB;
    float sf = 0.5f * (qc + 1.0f);
    soft_o[j] = mk * fminf(fmaxf(sf, 0.0f), 1.0f);
  }
  *(float4*)(out + base + p0) =
      make_float4(hard_o[0], hard_o[1], hard_o[2], hard_o[3]);
  *(float4*)(out + NL*NPIX + base + p0) =
      make_float4(soft_o[0], soft_o[1], soft_o[2], soft_o[3]);
}

extern "C" void kernel_launch(void* const* d_in, const int* in_sizes, int n_in,
                              void* d_out, int out_size, void* d_ws, size_t ws_size,
                              hipStream_t stream) {
  (void)in_sizes; (void)n_in; (void)out_size; (void)d_ws; (void)ws_size;
  const float* depth = (const float*)d_in[0];
  const float* als   = (const float*)d_in[1];
  const float* mask  = (const float*)d_in[2];
  const float* z_map = (const float*)d_in[3];
  float* out = (float*)d_out;
  // constants in double, replicating numpy, then rounded to f32
  double TANH = tan(2.0*atan(0.5*36.0/50.0)/2.0);
  double NEARc = 2.7 - sqrt(2.0)*2.7*TANH;
  double FARc  = 2.7 + sqrt(2.0)*2.7*TANH;
  float ozf = (float)(-2.0/(FARc-NEARc));
  float owf = (float)((-(FARc+NEARc))/(FARc-NEARc));
  float tanhf_ = (float)TANH;

  fused_kernel<<<NL*NPIX/1024, 256, 0, stream>>>(depth, mask, z_map, als, out,
                                                 tanhf_, ozf, owf);
}

// Round 8
// 159.070 us; speedup vs baseline: 1.0255x; 1.0255x over previous
//
#include <hip/hip_runtime.h>
#include <math.h>

// ShadowMapping forward: hard + soft shadow maps, fully fused, single kernel.
// R8: row-vectorized taps — each 3x3 stencil row (u-1,u,u+1) is ONE float4
//     load at ub=clamp(u-1,0,508) + v_cndmask tap select (ci = u-ub), cutting
//     vmem instructions 9->3 and wave line-transactions ~2.5x (R7 showed
//     VALUBusy 21%: gather-transaction/latency bound, not VALU).
//     Poly identity (R7), 3x3 blur (R6), geometry chain (R2) all validated.

#define RESN 512
#define NL 16
#define NPIX (RESN*RESN)

__global__ __launch_bounds__(256) void fused_kernel(
    const float* __restrict__ depth,
    const float* __restrict__ mask,
    const float* __restrict__ z_map,
    const float* __restrict__ als,
    float* __restrict__ out,
    float TANHF, float OZF, float OWF)
{
  #pragma clang fp contract(off)
  const float OFFS = -0.0642233295781f;
  const float CLB  = 0.4458709375254f;
  const float TWO_OVER_PI = 0.63661977236758134308f;
  // 4096 blocks: low 3 bits + bit 11 = light (XCD affinity: l === id mod 8),
  // bits [3..10] = 256 pixel-blocks of 1024 px.
  const int id = (int)blockIdx.x;
  const int l  = ((id >> 11) << 3) | (id & 7);
  const int pb = (id >> 3) & 255;
  const int p0 = (pb << 10) + ((int)threadIdx.x << 2);   // 4 consecutive px
  const int r  = p0 >> 9;
  const int c0 = p0 & 511;

  // ---- per-light uniforms (amortized over 4 pixels) ---------------------
  float xd = als[l*7+0], yd = als[l*7+1], zd = als[l*7+2], sg = als[l*7+3];
  float cosp = sqrtf(xd*xd + zd*zd);
  float cost = zd / cosp;
  float sint = xd / cosp;
  float e00 = cost,          e02 = -sint;
  float e10 = (-sint)*yd,    e11 = cosp,  e12 = (-cost)*yd;
  float e20 = cosp*sint,     e21 = yd,    e22 = cosp*cost;
  // radius-1 Gaussian, normalized over the full 21-tap sum (validated R6/R7)
  float sig = ((2.0f*(6.0f*sg + 1.0f)) - 1.0f) / 6.0f;
  float ivs = 1.0f/(sig*sig);
  float e1  = __builtin_amdgcn_exp2f(-0.72134752044448170368f*ivs);
  float e1sq = e1*e1;
  float e2  = e1sq*e1sq;
  float kinv = 1.0f/(1.0f + 2.0f*e1 + 2.0f*e2);
  float w0 = kinv, w1 = e1*kinv;

  const int base = l << 18;
  float4 dz4 = *(const float4*)(depth + p0);
  float4 mk4 = *(const float4*)(mask  + p0);
  float m1r = 2.0f * ((float)r / 512.0f + 0.0009765625f) - 1.0f;

  float hard_o[4], soft_o[4];
  #pragma unroll
  for (int j = 0; j < 4; ++j) {
    float dz = (j==0)?dz4.x:(j==1)?dz4.y:(j==2)?dz4.z:dz4.w;
    float mk = (j==0)?mk4.x:(j==1)?mk4.y:(j==2)?mk4.z:mk4.w;
    float m1c = 2.0f * ((float)(c0+j) / 512.0f + 0.0009765625f) - 1.0f;
    float tT = dz * TANHF;
    float qx = tT * m1c;
    float qy = tT * m1r;
    float qz = 2.7f - dz;
    // XLA dot emitter: sequential fmuladd over w (validated R2)
    float X1 = fmaf(qz, e02, qx * e00);
    float Y1 = fmaf(qz, e12, fmaf(qy, e11, qx * e10));
    float T2 = fmaf(qz, e22, fmaf(qy, e21, qx * e20));
    float Z1 = T2 + (-2.7f);
    float ZZ = (Z1 * OZF) + OWF;
    float uf = (X1 + 1.0f) * 256.0f;
    float vf = (Y1 + 1.0f) * 256.0f;
    int u = (int)uf; u = u < 0 ? 0 : (u > 511 ? 511 : u);
    int v = (int)vf; v = v < 0 ? 0 : (v > 511 ? 511 : v);
    float dd = 0.5f * (1.0f + ZZ);
    dd = fminf(fmaxf(dd, 0.0f), 1.0f);
    float dpo = dd + OFFS;

    // ---- 3 float4 row loads; taps selected by ci = u-ub ------------------
    // ub in [0,508]; taps L,C,R = loaded[ci-1], loaded[ci], loaded[ci+1]
    // (clamped into the vector; out-of-range selections carry zero weight).
    int ub = u - 1; ub = ub < 0 ? 0 : (ub > 508 ? 508 : ub);
    int ci = u - ub;                      // 0..3
    int v0 = v > 0 ? v - 1 : 0;
    int v2 = v < 511 ? v + 1 : 511;
    float4 rT = *(const float4*)(z_map + base + (v0 << 9) + ub);
    float4 rC = *(const float4*)(z_map + base + (v  << 9) + ub);
    float4 rB = *(const float4*)(z_map + base + (v2 << 9) + ub);

    auto selL = [&](const float4& f) {        // elem max(ci-1,0)
      return ci <= 1 ? f.x : (ci == 2 ? f.y : f.z);
    };
    auto selC = [&](const float4& f) {        // elem ci
      return ci == 0 ? f.x : (ci == 1 ? f.y : (ci == 2 ? f.z : f.w));
    };
    auto selR = [&](const float4& f) {        // elem min(ci+1,3)
      return ci == 0 ? f.y : (ci == 1 ? f.z : f.w);
    };
    float zg = selC(rC);

    float wuL = (u > 0)   ? w1 : 0.0f;
    float wuR = (u < 511) ? w1 : 0.0f;
    float wvT = (v > 0)   ? w1 : 0.0f;
    float wvB = (v < 511) ? w1 : 0.0f;

    // f = sum_{m odd<=7} (1/m) sin(m*pi*(z-dpo)) = s*P(s^2), s=sin(pi*(z-dpo))
    auto fval = [&](float z) {
      float s = __builtin_amdgcn_sinf(0.5f * (z - dpo));   // revolutions
      float t = s * s;
      return s * fmaf(t, fmaf(t, fmaf(t, -9.142857142857142f, 19.2f),
                              -13.333333333333334f), 4.0f);
    };

    float rowT = fmaf(wuL, fval(selL(rT)), fmaf(w0, fval(selC(rT)), wuR * fval(selR(rT))));
    float rowC = fmaf(wuL, fval(selL(rC)), fmaf(w0, fval(zg),       wuR * fval(selR(rC))));
    float rowB = fmaf(wuL, fval(selL(rB)), fmaf(w0, fval(selC(rB)), wuR * fval(selR(rB))));
    float q = TWO_OVER_PI * fmaf(wvT, rowT, fmaf(w0, rowC, wvB * rowB));

    float diff = fmaxf(dd - zg, 0.0f);
    hard_o[j] = mk * ((diff > 0.008f) ? 0.0f : 1.0f);
    float qc = fminf(fmaxf(q, -CLB), CLB) / CLB;
    float sf = 0.5f * (qc + 1.0f);
    soft_o[j] = mk * fminf(fmaxf(sf, 0.0f), 1.0f);
  }
  *(float4*)(out + base + p0) =
      make_float4(hard_o[0], hard_o[1], hard_o[2], hard_o[3]);
  *(float4*)(out + NL*NPIX + base + p0) =
      make_float4(soft_o[0], soft_o[1], soft_o[2], soft_o[3]);
}

extern "C" void kernel_launch(void* const* d_in, const int* in_sizes, int n_in,
                              void* d_out, int out_size, void* d_ws, size_t ws_size,
                              hipStream_t stream) {
  (void)in_sizes; (void)n_in; (void)out_size; (void)d_ws; (void)ws_size;
  const float* depth = (const float*)d_in[0];
  const float* als   = (const float*)d_in[1];
  const float* mask  = (const float*)d_in[2];
  const float* z_map = (const float*)d_in[3];
  float* out = (float*)d_out;
  // constants in double, replicating numpy, then rounded to f32
  double TANH = tan(2.0*atan(0.5*36.0/50.0)/2.0);
  double NEARc = 2.7 - sqrt(2.0)*2.7*TANH;
  double FARc  = 2.7 + sqrt(2.0)*2.7*TANH;
  float ozf = (float)(-2.0/(FARc-NEARc));
  float owf = (float)((-(FARc+NEARc))/(FARc-NEARc));
  float tanhf_ = (float)TANH;

  fused_kernel<<<NL*NPIX/1024, 256, 0, stream>>>(depth, mask, z_map, als, out,
                                                 tanhf_, ozf, owf);
}

// Round 9
// 132.262 us; speedup vs baseline: 1.2334x; 1.2027x over previous
//
#include <hip/hip_runtime.h>
#include <math.h>

// ShadowMapping forward: hard + soft shadow maps, fully fused, single kernel.
// R9: 5-tap plus-stencil — corner taps dropped (worst-case soft delta 0.0053,
//     budget 0.02; weights keep full 21-tap normalization). R6's best config
//     restored: 1 px/thread, 16K blocks, scalar taps (R8's unaligned float4
//     gathers caused 4x WRITE amplification and no speedup — kernel is bound
//     by scattered per-lane VMEM processing, so tap COUNT is the only lever).
//     Poly-sin identity (R7), geometry chain (R2) validated.

#define RESN 512
#define NL 16
#define NPIX (RESN*RESN)

__global__ __launch_bounds__(256) void fused_kernel(
    const float* __restrict__ depth,
    const float* __restrict__ mask,
    const float* __restrict__ z_map,
    const float* __restrict__ als,
    float* __restrict__ out,
    float TANHF, float OZF, float OWF)
{
  #pragma clang fp contract(off)
  const float OFFS = -0.0642233295781f;
  const float CLB  = 0.4458709375254f;
  const float TWO_OVER_PI = 0.63661977236758134308f;
  // XCD-affinity swizzle: block id === light (mod 8); each light's 1MB z
  // slice stays L2-resident on one XCD.
  const int id = (int)blockIdx.x;
  const int l  = ((id >> 13) << 3) | (id & 7);
  const int pb = (id >> 3) & 1023;
  const int p  = (pb << 8) + (int)threadIdx.x;
  const int r = p >> 9, c = p & 511;

  // ---- per-light uniforms ----------------------------------------------
  float xd = als[l*7+0], yd = als[l*7+1], zd = als[l*7+2], sg = als[l*7+3];
  float cosp = sqrtf(xd*xd + zd*zd);
  float cost = zd / cosp;
  float sint = xd / cosp;
  float e00 = cost,          e02 = -sint;
  float e10 = (-sint)*yd,    e11 = cosp,  e12 = (-cost)*yd;
  float e20 = cosp*sint,     e21 = yd,    e22 = cosp*cost;
  // radius-1 Gaussian, normalized over the full 21-tap sum (validated R6)
  float sig = ((2.0f*(6.0f*sg + 1.0f)) - 1.0f) / 6.0f;
  float ivs = 1.0f/(sig*sig);
  float e1  = __builtin_amdgcn_exp2f(-0.72134752044448170368f*ivs);
  float e1sq = e1*e1;
  float e2  = e1sq*e1sq;
  float kinv = 1.0f/(1.0f + 2.0f*e1 + 2.0f*e2);
  float w0 = kinv, w1 = e1*kinv;

  // ---- geometry (bit-identical to validated chain) ---------------------
  float dz = depth[p];
  float mk = mask[p];
  float m1c = 2.0f * ((float)c / 512.0f + 0.0009765625f) - 1.0f;
  float m1r = 2.0f * ((float)r / 512.0f + 0.0009765625f) - 1.0f;
  float tT = dz * TANHF;
  float qx = tT * m1c;
  float qy = tT * m1r;
  float qz = 2.7f - dz;
  // XLA dot emitter: sequential fmuladd over w (validated R2)
  float X1 = fmaf(qz, e02, qx * e00);
  float Y1 = fmaf(qz, e12, fmaf(qy, e11, qx * e10));
  float T2 = fmaf(qz, e22, fmaf(qy, e21, qx * e20));
  float Z1 = T2 + (-2.7f);
  float ZZ = (Z1 * OZF) + OWF;
  float uf = (X1 + 1.0f) * 256.0f;
  float vf = (Y1 + 1.0f) * 256.0f;
  int u = (int)uf; u = u < 0 ? 0 : (u > 511 ? 511 : u);
  int v = (int)vf; v = v < 0 ? 0 : (v > 511 ? 511 : v);
  float dd = 0.5f * (1.0f + ZZ);
  dd = fminf(fmaxf(dd, 0.0f), 1.0f);
  float dpo = dd + OFFS;

  // ---- 5 plus-stencil taps (clamped indices; OOB -> zero weight) --------
  const int base = l << 18;
  int u0 = u > 0 ? u - 1 : 0;
  int u2 = u < 511 ? u + 1 : 511;
  int v0 = v > 0 ? v - 1 : 0;
  int v2 = v < 511 ? v + 1 : 511;
  const float* zrC = z_map + base + (v << 9);
  float zT = z_map[base + (v0 << 9) + u];
  float zL = zrC[u0];
  float zg = zrC[u];
  float zR = zrC[u2];
  float zB = z_map[base + (v2 << 9) + u];

  float wuL = (u > 0)   ? w1 : 0.0f;
  float wuR = (u < 511) ? w1 : 0.0f;
  float wvT = (v > 0)   ? w1 : 0.0f;
  float wvB = (v < 511) ? w1 : 0.0f;

  // f = sum_{m odd<=7} (1/m) sin(m*pi*(z-dpo)) = s*P(s^2), s = sin(pi*(z-dpo))
  auto fval = [&](float z) {
    float s = __builtin_amdgcn_sinf(0.5f * (z - dpo));   // revolutions
    float t = s * s;
    return s * fmaf(t, fmaf(t, fmaf(t, -9.142857142857142f, 19.2f),
                            -13.333333333333334f), 4.0f);
  };

  float qs = w0 * fval(zg);
  qs = fmaf(wvT, fval(zT), qs);
  qs = fmaf(wvB, fval(zB), qs);
  qs = fmaf(wuL, fval(zL), qs);
  qs = fmaf(wuR, fval(zR), qs);
  float q = TWO_OVER_PI * (w0 * qs);

  // ---- outputs ----------------------------------------------------------
  float diff = fmaxf(dd - zg, 0.0f);
  float hard = (diff > 0.008f) ? 0.0f : 1.0f;
  out[base + p] = mk * hard;
  float qc = fminf(fmaxf(q, -CLB), CLB) / CLB;
  float sf = 0.5f * (qc + 1.0f);
  sf = fminf(fmaxf(sf, 0.0f), 1.0f);
  out[(NL*NPIX) + base + p] = mk * sf;
}

extern "C" void kernel_launch(void* const* d_in, const int* in_sizes, int n_in,
                              void* d_out, int out_size, void* d_ws, size_t ws_size,
                              hipStream_t stream) {
  (void)in_sizes; (void)n_in; (void)out_size; (void)d_ws; (void)ws_size;
  const float* depth = (const float*)d_in[0];
  const float* als   = (const float*)d_in[1];
  const float* mask  = (const float*)d_in[2];
  const float* z_map = (const float*)d_in[3];
  float* out = (float*)d_out;
  // constants in double, replicating numpy, then rounded to f32
  double TANH = tan(2.0*atan(0.5*36.0/50.0)/2.0);
  double NEARc = 2.7 - sqrt(2.0)*2.7*TANH;
  double FARc  = 2.7 + sqrt(2.0)*2.7*TANH;
  float ozf = (float)(-2.0/(FARc-NEARc));
  float owf = (float)((-(FARc+NEARc))/(FARc-NEARc));
  float tanhf_ = (float)TANH;

  fused_kernel<<<NL*NPIX/256, 256, 0, stream>>>(depth, mask, z_map, als, out,
                                                tanhf_, ozf, owf);
}

// Round 10
// 131.705 us; speedup vs baseline: 1.2386x; 1.0042x over previous
//
#include <hip/hip_runtime.h>
#include <math.h>

// ShadowMapping forward: hard + soft shadow maps, fully fused, single kernel.
// R10: (a) 512-thread blocks (one image row per block, grid 8192) to break the
//      ~55% occupancy plateau (workgroup-slot-limit theory); (b) L+C taps as
//      one 8B dwordx2 (packed, 4B-aligned) -> 4 scattered lane-requests/px
//      (was 5). Stores unchanged from R9 (R8 showed unaligned 16B gathers
//      correlate with 4x WRITE amplification). 5-tap plus-stencil (R9),
//      poly-sin identity (R7), geometry chain (R2) all validated.

#define RESN 512
#define NL 16
#define NPIX (RESN*RESN)

struct __attribute__((packed, aligned(4))) F2 { float x, y; };

__global__ __launch_bounds__(512) void fused_kernel(
    const float* __restrict__ depth,
    const float* __restrict__ mask,
    const float* __restrict__ z_map,
    const float* __restrict__ als,
    float* __restrict__ out,
    float TANHF, float OZF, float OWF)
{
  #pragma clang fp contract(off)
  const float OFFS = -0.0642233295781f;
  const float CLB  = 0.4458709375254f;
  const float TWO_OVER_PI = 0.63661977236758134308f;
  // 8192 blocks: l = low 3 bits + bit 12 (XCD affinity: l === id mod 8);
  // bits [3..11] = image row. One row (512 px) per block.
  const int id = (int)blockIdx.x;
  const int l  = ((id >> 12) << 3) | (id & 7);
  const int r  = (id >> 3) & 511;
  const int c  = (int)threadIdx.x;
  const int p  = (r << 9) + c;

  // ---- per-light uniforms ----------------------------------------------
  float xd = als[l*7+0], yd = als[l*7+1], zd = als[l*7+2], sg = als[l*7+3];
  float cosp = sqrtf(xd*xd + zd*zd);
  float cost = zd / cosp;
  float sint = xd / cosp;
  float e00 = cost,          e02 = -sint;
  float e10 = (-sint)*yd,    e11 = cosp,  e12 = (-cost)*yd;
  float e20 = cosp*sint,     e21 = yd,    e22 = cosp*cost;
  // radius-1 Gaussian, normalized over the full 21-tap sum (validated R6)
  float sig = ((2.0f*(6.0f*sg + 1.0f)) - 1.0f) / 6.0f;
  float ivs = 1.0f/(sig*sig);
  float e1  = __builtin_amdgcn_exp2f(-0.72134752044448170368f*ivs);
  float e1sq = e1*e1;
  float e2  = e1sq*e1sq;
  float kinv = 1.0f/(1.0f + 2.0f*e1 + 2.0f*e2);
  float w0 = kinv, w1 = e1*kinv;

  // ---- geometry (bit-identical to validated chain) ---------------------
  float dz = depth[p];
  float mk = mask[p];
  float m1c = 2.0f * ((float)c / 512.0f + 0.0009765625f) - 1.0f;
  float m1r = 2.0f * ((float)r / 512.0f + 0.0009765625f) - 1.0f;
  float tT = dz * TANHF;
  float qx = tT * m1c;
  float qy = tT * m1r;
  float qz = 2.7f - dz;
  // XLA dot emitter: sequential fmuladd over w (validated R2)
  float X1 = fmaf(qz, e02, qx * e00);
  float Y1 = fmaf(qz, e12, fmaf(qy, e11, qx * e10));
  float T2 = fmaf(qz, e22, fmaf(qy, e21, qx * e20));
  float Z1 = T2 + (-2.7f);
  float ZZ = (Z1 * OZF) + OWF;
  float uf = (X1 + 1.0f) * 256.0f;
  float vf = (Y1 + 1.0f) * 256.0f;
  int u = (int)uf; u = u < 0 ? 0 : (u > 511 ? 511 : u);
  int v = (int)vf; v = v < 0 ? 0 : (v > 511 ? 511 : v);
  float dd = 0.5f * (1.0f + ZZ);
  dd = fminf(fmaxf(dd, 0.0f), 1.0f);
  float dpo = dd + OFFS;

  // ---- plus-stencil: 4 scattered requests (T, B, LC-pair, R) ------------
  const int base = l << 18;
  int u0 = u > 0 ? u - 1 : 0;           // pair base: [u0, u0+1]
  int u2 = u < 511 ? u + 1 : 511;
  int v0 = v > 0 ? v - 1 : 0;
  int v2 = v < 511 ? v + 1 : 511;
  const float* zrC = z_map + base + (v << 9);
  float zT = z_map[base + (v0 << 9) + u];
  F2 zLC = *(const F2*)(zrC + u0);       // u>=1: [L,C]; u==0: [C, z(1)]
  float zR = zrC[u2];
  float zB = z_map[base + (v2 << 9) + u];
  float zg = (u == 0) ? zLC.x : zLC.y;
  float zL = zLC.x;                      // wuL=0 when u==0 -> value unused

  float wuL = (u > 0)   ? w1 : 0.0f;
  float wuR = (u < 511) ? w1 : 0.0f;
  float wvT = (v > 0)   ? w1 : 0.0f;
  float wvB = (v < 511) ? w1 : 0.0f;

  // f = sum_{m odd<=7} (1/m) sin(m*pi*(z-dpo)) = s*P(s^2), s = sin(pi*(z-dpo))
  auto fval = [&](float z) {
    float s = __builtin_amdgcn_sinf(0.5f * (z - dpo));   // revolutions
    float t = s * s;
    return s * fmaf(t, fmaf(t, fmaf(t, -9.142857142857142f, 19.2f),
                            -13.333333333333334f), 4.0f);
  };

  float qs = w0 * fval(zg);
  qs = fmaf(wvT, fval(zT), qs);
  qs = fmaf(wvB, fval(zB), qs);
  qs = fmaf(wuL, fval(zL), qs);
  qs = fmaf(wuR, fval(zR), qs);
  float q = TWO_OVER_PI * (w0 * qs);

  // ---- outputs ----------------------------------------------------------
  float diff = fmaxf(dd - zg, 0.0f);
  float hard = (diff > 0.008f) ? 0.0f : 1.0f;
  out[base + p] = mk * hard;
  float qc = fminf(fmaxf(q, -CLB), CLB) / CLB;
  float sf = 0.5f * (qc + 1.0f);
  sf = fminf(fmaxf(sf, 0.0f), 1.0f);
  out[(NL*NPIX) + base + p] = mk * sf;
}

extern "C" void kernel_launch(void* const* d_in, const int* in_sizes, int n_in,
                              void* d_out, int out_size, void* d_ws, size_t ws_size,
                              hipStream_t stream) {
  (void)in_sizes; (void)n_in; (void)out_size; (void)d_ws; (void)ws_size;
  const float* depth = (const float*)d_in[0];
  const float* als   = (const float*)d_in[1];
  const float* mask  = (const float*)d_in[2];
  const float* z_map = (const float*)d_in[3];
  float* out = (float*)d_out;
  // constants in double, replicating numpy, then rounded to f32
  double TANH = tan(2.0*atan(0.5*36.0/50.0)/2.0);
  double NEARc = 2.7 - sqrt(2.0)*2.7*TANH;
  double FARc  = 2.7 + sqrt(2.0)*2.7*TANH;
  float ozf = (float)(-2.0/(FARc-NEARc));
  float owf = (float)((-(FARc+NEARc))/(FARc-NEARc));
  float tanhf_ = (float)TANH;

  fused_kernel<<<NL*NPIX/512, 512, 0, stream>>>(depth, mask, z_map, als, out,
                                                tanhf_, ozf, owf);
}

// Round 11
// 124.718 us; speedup vs baseline: 1.3080x; 1.0560x over previous
//
#include <hip/hip_runtime.h>
#include <math.h>

// ShadowMapping forward: hard + soft shadow maps.
// R11: (a) per-light uniforms (3 divides, sqrt, exp2, weights) moved to a
//      16-thread setup kernel; main reads them as block-uniform SGPR loads
//      (CDNA has no scalar FP pipe — that code was ~90 VALU/thread).
//      (b) light-adaptive taps: if w1 < 3e-3, side taps add < 0.0082 to soft
//      (Gibbs-bound 0.95, /2*CLB) -> 1-tap mode for ~half the lights;
//      uniform per-block branch. Tap model (validated R6..R10):
//      t = 40.7us + 5.25us/tap, TA-line-bound.
//      5-tap plus-stencil (R9), poly-sin (R7), geometry chain (R2) validated.

#define RESN 512
#define NL 16
#define NPIX (RESN*RESN)

__global__ void setup_kernel(const float* __restrict__ als,
                             float* __restrict__ lp) {
  #pragma clang fp contract(off)
  int l = (int)threadIdx.x;
  if (l >= NL) return;
  float xd = als[l*7+0], yd = als[l*7+1], zd = als[l*7+2], sg = als[l*7+3];
  float cosp = sqrtf(xd*xd + zd*zd);
  float cost = zd / cosp;
  float sint = xd / cosp;
  float* o = lp + l*16;
  o[0] = cost;               // e00
  o[1] = -sint;              // e02
  o[2] = (-sint)*yd;         // e10
  o[3] = cosp;               // e11
  o[4] = (-cost)*yd;         // e12
  o[5] = cosp*sint;          // e20
  o[6] = yd;                 // e21
  o[7] = cosp*cost;          // e22
  // radius-1 Gaussian, normalized over the full 21-tap sum (validated R6)
  float sig = ((2.0f*(6.0f*sg + 1.0f)) - 1.0f) / 6.0f;
  float ivs = 1.0f/(sig*sig);
  float e1  = __builtin_amdgcn_exp2f(-0.72134752044448170368f*ivs);
  float e1sq = e1*e1;
  float e2  = e1sq*e1sq;
  float kinv = 1.0f/(1.0f + 2.0f*e1 + 2.0f*e2);
  o[8] = kinv;               // w0
  o[9] = e1*kinv;            // w1
  o[10] = (e1*kinv >= 0.003f) ? 1.0f : 0.0f;   // 5-tap mode flag
  o[11] = kinv*kinv;         // w0^2 (1-tap path)
  o[12] = o[13] = o[14] = o[15] = 0.0f;
}

__global__ __launch_bounds__(512) void fused_kernel(
    const float* __restrict__ depth,
    const float* __restrict__ mask,
    const float* __restrict__ z_map,
    const float* __restrict__ lp,
    float* __restrict__ out,
    float TANHF, float OZF, float OWF)
{
  #pragma clang fp contract(off)
  const float OFFS = -0.0642233295781f;
  const float CLB  = 0.4458709375254f;
  const float TWO_OVER_PI = 0.63661977236758134308f;
  // 8192 blocks: l = low 3 bits + bit 12 (XCD affinity: l === id mod 8);
  // bits [3..11] = image row. One row (512 px) per block.
  const int id = (int)blockIdx.x;
  const int l  = ((id >> 12) << 3) | (id & 7);
  const int r  = (id >> 3) & 511;
  const int c  = (int)threadIdx.x;
  const int p  = (r << 9) + c;

  // block-uniform scalar loads (setup kernel did the VALU-heavy math)
  const float* P = lp + l*16;
  float e00 = P[0], e02 = P[1], e10 = P[2], e11 = P[3], e12 = P[4];
  float e20 = P[5], e21 = P[6], e22 = P[7];
  float w0 = P[8], w1 = P[9];
  bool five_tap = P[10] != 0.0f;
  float w0sq = P[11];

  // ---- geometry (bit-identical to validated chain) ---------------------
  float dz = depth[p];
  float mk = mask[p];
  float m1c = 2.0f * ((float)c / 512.0f + 0.0009765625f) - 1.0f;
  float m1r = 2.0f * ((float)r / 512.0f + 0.0009765625f) - 1.0f;
  float tT = dz * TANHF;
  float qx = tT * m1c;
  float qy = tT * m1r;
  float qz = 2.7f - dz;
  // XLA dot emitter: sequential fmuladd over w (validated R2)
  float X1 = fmaf(qz, e02, qx * e00);
  float Y1 = fmaf(qz, e12, fmaf(qy, e11, qx * e10));
  float T2 = fmaf(qz, e22, fmaf(qy, e21, qx * e20));
  float Z1 = T2 + (-2.7f);
  float ZZ = (Z1 * OZF) + OWF;
  float uf = (X1 + 1.0f) * 256.0f;
  float vf = (Y1 + 1.0f) * 256.0f;
  int u = (int)uf; u = u < 0 ? 0 : (u > 511 ? 511 : u);
  int v = (int)vf; v = v < 0 ? 0 : (v > 511 ? 511 : v);
  float dd = 0.5f * (1.0f + ZZ);
  dd = fminf(fmaxf(dd, 0.0f), 1.0f);
  float dpo = dd + OFFS;

  const int base = l << 18;
  const float* zrC = z_map + base + (v << 9);
  float zg = zrC[u];

  // f = sum_{m odd<=7} (1/m) sin(m*pi*(z-dpo)) = s*P(s^2), s = sin(pi*(z-dpo))
  auto fval = [&](float z) {
    float s = __builtin_amdgcn_sinf(0.5f * (z - dpo));   // revolutions
    float t = s * s;
    return s * fmaf(t, fmaf(t, fmaf(t, -9.142857142857142f, 19.2f),
                            -13.333333333333334f), 4.0f);
  };

  float q;
  if (five_tap) {
    // ---- 5 plus-stencil taps (clamped indices; OOB -> zero weight) ------
    int u0 = u > 0 ? u - 1 : 0;
    int u2 = u < 511 ? u + 1 : 511;
    int v0 = v > 0 ? v - 1 : 0;
    int v2 = v < 511 ? v + 1 : 511;
    float zT = z_map[base + (v0 << 9) + u];
    float zL = zrC[u0];
    float zR = zrC[u2];
    float zB = z_map[base + (v2 << 9) + u];
    float wuL = (u > 0)   ? w1 : 0.0f;
    float wuR = (u < 511) ? w1 : 0.0f;
    float wvT = (v > 0)   ? w1 : 0.0f;
    float wvB = (v < 511) ? w1 : 0.0f;
    float qs = w0 * fval(zg);
    qs = fmaf(wvT, fval(zT), qs);
    qs = fmaf(wvB, fval(zB), qs);
    qs = fmaf(wuL, fval(zL), qs);
    qs = fmaf(wuR, fval(zR), qs);
    q = TWO_OVER_PI * (w0 * qs);
  } else {
    // ---- 1-tap mode: side weights < 3e-3, dropped (soft delta < 0.0082) --
    q = TWO_OVER_PI * (w0sq * fval(zg));
  }

  // ---- outputs ----------------------------------------------------------
  float diff = fmaxf(dd - zg, 0.0f);
  float hard = (diff > 0.008f) ? 0.0f : 1.0f;
  out[base + p] = mk * hard;
  float qc = fminf(fmaxf(q, -CLB), CLB) / CLB;
  float sf = 0.5f * (qc + 1.0f);
  sf = fminf(fmaxf(sf, 0.0f), 1.0f);
  out[(NL*NPIX) + base + p] = mk * sf;
}

extern "C" void kernel_launch(void* const* d_in, const int* in_sizes, int n_in,
                              void* d_out, int out_size, void* d_ws, size_t ws_size,
                              hipStream_t stream) {
  (void)in_sizes; (void)n_in; (void)out_size; (void)ws_size;
  const float* depth = (const float*)d_in[0];
  const float* als   = (const float*)d_in[1];
  const float* mask  = (const float*)d_in[2];
  const float* z_map = (const float*)d_in[3];
  float* out = (float*)d_out;
  float* lp = (float*)d_ws;                       // 16 lights x 16 floats = 1KB
  // constants in double, replicating numpy, then rounded to f32
  double TANH = tan(2.0*atan(0.5*36.0/50.0)/2.0);
  double NEARc = 2.7 - sqrt(2.0)*2.7*TANH;
  double FARc  = 2.7 + sqrt(2.0)*2.7*TANH;
  float ozf = (float)(-2.0/(FARc-NEARc));
  float owf = (float)((-(FARc+NEARc))/(FARc-NEARc));
  float tanhf_ = (float)TANH;

  setup_kernel<<<1, 64, 0, stream>>>(als, lp);
  fused_kernel<<<NL*NPIX/512, 512, 0, stream>>>(depth, mask, z_map, lp, out,
                                                tanhf_, ozf, owf);
}